// Round 1
// baseline (1169.042 us; speedup 1.0000x reference)
//
#include <hip/hip_runtime.h>

#define T_STEPS 512
#define BATCH   2048
#define DIN     128
#define NH      16
#define COMB    (DIN + NH)

__device__ __forceinline__ float rcpf(float x)  { return __builtin_amdgcn_rcpf(x); }
__device__ __forceinline__ float sigmf(float x) { return rcpf(1.f + __expf(-x)); }
__device__ __forceinline__ float tanhf_(float x){ float e = __expf(2.f * x); return (e - 1.f) * rcpf(e + 1.f); }

// value from lane (k - D) within the 16-lane row; lanes k < D receive 1.0f (mul identity)
template <int D>
__device__ __forceinline__ float scan_shr(float v) {
    int r = __builtin_amdgcn_update_dpp(0x3f800000, __float_as_int(v),
                                        0x110 | D, 0xF, 0xF, false);
    return __int_as_float(r);
}

__global__ __launch_bounds__(64, 2) void qlstm_kernel(
    const float* __restrict__ x,
    const float* __restrict__ Wf, const float* __restrict__ bf,
    const float* __restrict__ Wi, const float* __restrict__ bi,
    const float* __restrict__ Wu, const float* __restrict__ bu,
    const float* __restrict__ Wo, const float* __restrict__ bo,
    const float* __restrict__ thf, const float* __restrict__ thi,
    const float* __restrict__ thu, const float* __restrict__ tho,
    float* __restrict__ out)
{
    const int lane = threadIdx.x;      // 64 threads = 1 wave per block
    const int k    = lane & 15;        // gate-output index
    const int q    = lane >> 4;        // K-chunk (4 chunks of 32 x-elems + 4 h-elems)
    const int b    = blockIdx.x;       // batch element

    const float* Wg[4] = {Wf, Wi, Wu, Wo};
    const float* bg[4] = {bf, bi, bu, bo};
    const float* tg[4] = {thf, thi, thu, tho};

    // persistent per-lane weights: 4 gates x (32 x-weights + 4 h-weights)
    float w[4][32], wh[4][4], bt[4];
#pragma unroll
    for (int g = 0; g < 4; ++g) {
        const float* Wr = Wg[g] + k * COMB;
#pragma unroll
        for (int j = 0; j < 32; ++j) w[g][j] = Wr[q * 32 + j];
#pragma unroll
        for (int kk = 0; kk < 4; ++kk) wh[g][kk] = Wr[DIN + q * 4 + kk];
        bt[g] = bg[g][k] + tg[g][k];   // bias + theta folded (arg of cos)
    }

    float h = 0.f, c = 0.f;
    float cvA[32], cvB[32];

    // x[t][b][q*32 + j]
    auto xrow = [&](int t) -> const float* {
        return x + ((size_t)t * BATCH + b) * DIN + q * 32;
    };
    auto loadx = [&](float (&cv)[32], const float* p) {
#pragma unroll
        for (int j4 = 0; j4 < 8; ++j4) {
            const float4 v = *(const float4*)(p + j4 * 4);
            cv[j4 * 4 + 0] = v.x; cv[j4 * 4 + 1] = v.y;
            cv[j4 * 4 + 2] = v.z; cv[j4 * 4 + 3] = v.w;
        }
    };

    float* op = out + (size_t)b * NH + k;          // outputs[t][b][k], advanced per step

    auto step = [&](int t, float (&cv)[32]) {
        float acc[4] = {0.f, 0.f, 0.f, 0.f};
        // x-part: 32 K-elems x 4 gates
#pragma unroll
        for (int j = 0; j < 32; ++j) {
#pragma unroll
            for (int g = 0; g < 4; ++g) acc[g] += cv[j] * w[g][j];
        }
        // h-part: this lane covers h[q*4 .. q*4+3]
#pragma unroll
        for (int kk = 0; kk < 4; ++kk) {
            const float hv = __shfl(h, q * 4 + kk, 64);
#pragma unroll
            for (int g = 0; g < 4; ++g) acc[g] += hv * wh[g][kk];
        }
        // reduce the 4 K-chunks (lanes k, k+16, k+32, k+48), then cos(z + theta)
#pragma unroll
        for (int g = 0; g < 4; ++g) {
            acc[g] += __shfl_xor(acc[g], 16, 64);
            acc[g] += __shfl_xor(acc[g], 32, 64);
            acc[g] = __cosf(acc[g] + bt[g]);
        }
        // segmented (16-lane) inclusive cumprod via DPP row-shift
#pragma unroll
        for (int g = 0; g < 4; ++g) {
            acc[g] *= scan_shr<1>(acc[g]);
            acc[g] *= scan_shr<2>(acc[g]);
            acc[g] *= scan_shr<4>(acc[g]);
            acc[g] *= scan_shr<8>(acc[g]);
        }
        const float f  = sigmf(acc[0]);
        const float i_ = sigmf(acc[1]);
        const float u  = tanhf_(acc[2]);
        const float o  = sigmf(acc[3]);
        c = f * c + i_ * u;
        h = o * tanhf_(c);
        if (q == 0) *op = h;                        // 16 lanes -> one 64B store
        op += (size_t)BATCH * NH;
    };

    loadx(cvA, xrow(0));
    for (int t = 0; t < T_STEPS; t += 2) {
        loadx(cvB, xrow(t + 1));                    // prefetch t+1 (t+1 <= 511 always)
        step(t, cvA);
        const int tn = (t + 2 < T_STEPS) ? t + 2 : T_STEPS - 1;
        loadx(cvA, xrow(tn));                       // prefetch t+2 (clamped)
        step(t + 1, cvB);
    }

    if (q == 0) {                                   // hx, cx
        const size_t base = (size_t)T_STEPS * BATCH * NH;
        out[base + (size_t)b * NH + k] = h;
        out[base + (size_t)BATCH * NH + (size_t)b * NH + k] = c;
    }
}

extern "C" void kernel_launch(void* const* d_in, const int* in_sizes, int n_in,
                              void* d_out, int out_size, void* d_ws, size_t ws_size,
                              hipStream_t stream) {
    const float* x   = (const float*)d_in[0];
    const float* Wf  = (const float*)d_in[1];
    const float* bf  = (const float*)d_in[2];
    const float* Wi  = (const float*)d_in[3];
    const float* bi  = (const float*)d_in[4];
    const float* Wu  = (const float*)d_in[5];
    const float* bu  = (const float*)d_in[6];
    const float* Wo  = (const float*)d_in[7];
    const float* bo  = (const float*)d_in[8];
    const float* thf = (const float*)d_in[9];
    const float* thi = (const float*)d_in[10];
    const float* thu = (const float*)d_in[11];
    const float* tho = (const float*)d_in[12];

    qlstm_kernel<<<dim3(BATCH), dim3(64), 0, stream>>>(
        x, Wf, bf, Wi, bi, Wu, bu, Wo, bo, thf, thi, thu, tho, (float*)d_out);
}